// Round 7
// baseline (432.308 us; speedup 1.0000x reference)
//
#include <hip/hip_runtime.h>
#include <hip/hip_bf16.h>
#include <math.h>

#define D 128
#define H 4
#define NEG_SLOPE 0.2f
#define LN_EPS 1e-5f

__device__ __forceinline__ float lrelu(float v) {
    return v > 0.f ? v : NEG_SLOPE * v;
}

// ---------- per-destination in-degree histogram (int atomics only) ----------
__global__ void k_count(const int* __restrict__ ei, int* __restrict__ cnt, int E) {
    int e = blockIdx.x * blockDim.x + threadIdx.x;
    if (e >= E) return;
    atomicAdd(&cnt[ei[E + e]], 1);
}

// ---------- hierarchical exclusive scan of cnt[N] -> off[N+1] ----------
__global__ void k_scan_part(const int* __restrict__ cnt, int* __restrict__ off,
                            int* __restrict__ bsum, int N) {
    __shared__ int sm[256];
    int i = blockIdx.x * 256 + threadIdx.x;
    int v = (i < N) ? cnt[i] : 0;
    sm[threadIdx.x] = v;
    __syncthreads();
    #pragma unroll
    for (int o = 1; o < 256; o <<= 1) {
        int t = (threadIdx.x >= (unsigned)o) ? sm[threadIdx.x - o] : 0;
        __syncthreads();
        sm[threadIdx.x] += t;
        __syncthreads();
    }
    if (i < N) off[i] = sm[threadIdx.x];
    if (threadIdx.x == 255) bsum[blockIdx.x] = sm[255];
}

__global__ void k_scan_top(int* __restrict__ bsum, int* __restrict__ off,
                           int NB, int N) {
    __shared__ int sm[256];
    int v = (threadIdx.x < (unsigned)NB) ? bsum[threadIdx.x] : 0;
    sm[threadIdx.x] = v;
    __syncthreads();
    #pragma unroll
    for (int o = 1; o < 256; o <<= 1) {
        int t = (threadIdx.x >= (unsigned)o) ? sm[threadIdx.x - o] : 0;
        __syncthreads();
        sm[threadIdx.x] += t;
        __syncthreads();
    }
    if (threadIdx.x < (unsigned)NB) bsum[threadIdx.x] = sm[threadIdx.x] - v;
    if (threadIdx.x == 255) off[N] = sm[255];
}

__global__ void k_scan_add(const int* __restrict__ cnt, int* __restrict__ off,
                           const int* __restrict__ bsum, int N) {
    int i = blockIdx.x * 256 + threadIdx.x;
    if (i < N) off[i] = off[i] - cnt[i] + bsum[blockIdx.x];
}

// ---------- CSR fill: adj2[slot] = {src, edge_id} (one 8B store) ----------
__global__ void k_fill(const int* __restrict__ ei, const int* __restrict__ off,
                       int* __restrict__ pos, int2* __restrict__ adj2, int E) {
    int e = blockIdx.x * blockDim.x + threadIdx.x;
    if (e >= E) return;
    int dst = ei[E + e];
    int slot = off[dst] + atomicAdd(&pos[dst], 1);
    adj2[slot] = make_int2(ei[e], e);
}

// ---------- GEMM: C[N,128] = A[N,128] @ W[128,128] ----------
// 32 rows x 128 cols per 256-thread block (LDS 17.4 KB -> 8 blocks/CU).
// Per thread: 2 rows x 8 cols register tile.
// MODE 1: A explicit, bf16 out + fused attention dots.
// MODE 2: A synthesized from scatter-mean (x gathered via CSR, W_edge, b_edge),
//         f32 out + bias.
template <int MODE>
__global__ __launch_bounds__(256) void k_gemm(
        const float* __restrict__ A, const float* __restrict__ W,
        const float* __restrict__ bias, float* __restrict__ C,
        __hip_bfloat16* __restrict__ xhb, float* __restrict__ a_s,
        float* __restrict__ a_d, const float* __restrict__ att_s,
        const float* __restrict__ att_d,
        const float* __restrict__ x, const int2* __restrict__ adj2,
        const int* __restrict__ off,
        const float* __restrict__ W_edge, const float* __restrict__ b_edge,
        int N) {
    __shared__ float As[32][132];
    int tid = threadIdx.x;
    int n0 = blockIdx.x * 32;

    if (MODE == 2) {
        __shared__ float rowf[32][4];
        // gather-sum raw 3-dim edge features: 8 threads per row
        {
            int r = tid >> 3, t8 = tid & 7;
            int n = n0 + r;
            float s0 = 0.f, s1 = 0.f, s2 = 0.f;
            int degv = 0;
            if (n < N) {
                int beg = off[n], end = off[n + 1];
                degv = end - beg;
                for (int p = beg + t8; p < end; p += 8) {
                    const float* xr = x + (size_t)adj2[p].y * 3;
                    s0 += xr[0]; s1 += xr[1]; s2 += xr[2];
                }
            }
            #pragma unroll
            for (int o = 1; o < 8; o <<= 1) {
                s0 += __shfl_xor(s0, o);
                s1 += __shfl_xor(s1, o);
                s2 += __shfl_xor(s2, o);
            }
            if (t8 == 0)
                *reinterpret_cast<float4*>(rowf[r]) =
                    make_float4(s0, s1, s2, (float)degv);
        }
        __syncthreads();
        int d = tid & 127;
        float we0 = W_edge[d], we1 = W_edge[D + d], we2 = W_edge[2 * D + d];
        float be = b_edge[d];
        for (int r = tid >> 7; r < 32; r += 2) {
            float4 rv = *reinterpret_cast<float4*>(rowf[r]);
            float c = rv.w;
            As[r][d] = (rv.x * we0 + rv.y * we1 + rv.z * we2 + c * be)
                       / fmaxf(c, 1.f);
        }
    } else {
        // stage 32 rows x 128 cols via float4: 1024 float4s, 4 per thread
        #pragma unroll
        for (int j = 0; j < 4; j++) {
            int i = tid + j * 256;
            int r = i >> 5, q = i & 31;
            int n = n0 + r;
            float4 v = make_float4(0.f, 0.f, 0.f, 0.f);
            if (n < N) v = reinterpret_cast<const float4*>(A)[(size_t)n * 32 + q];
            *reinterpret_cast<float4*>(&As[r][q * 4]) = v;
        }
    }
    __syncthreads();

    int tx = tid & 15, ty = tid >> 4;
    int c0 = tx * 8, r0 = ty * 2;
    float acc[2][8];
    #pragma unroll
    for (int r = 0; r < 2; r++)
        #pragma unroll
        for (int c = 0; c < 8; c++) acc[r][c] = 0.f;

    const float4* Wv = reinterpret_cast<const float4*>(W);
    #pragma unroll 2
    for (int k4 = 0; k4 < 32; k4++) {
        float4 a0 = *reinterpret_cast<const float4*>(&As[r0][k4 * 4]);
        float4 a1 = *reinterpret_cast<const float4*>(&As[r0 + 1][k4 * 4]);
        #pragma unroll
        for (int j = 0; j < 4; j++) {
            int k = k4 * 4 + j;
            float4 w0 = Wv[k * 32 + tx * 2];
            float4 w1 = Wv[k * 32 + tx * 2 + 1];
            float av0 = (&a0.x)[j];
            float av1 = (&a1.x)[j];
            acc[0][0] += av0 * w0.x; acc[0][1] += av0 * w0.y;
            acc[0][2] += av0 * w0.z; acc[0][3] += av0 * w0.w;
            acc[0][4] += av0 * w1.x; acc[0][5] += av0 * w1.y;
            acc[0][6] += av0 * w1.z; acc[0][7] += av0 * w1.w;
            acc[1][0] += av1 * w0.x; acc[1][1] += av1 * w0.y;
            acc[1][2] += av1 * w0.z; acc[1][3] += av1 * w0.w;
            acc[1][4] += av1 * w1.x; acc[1][5] += av1 * w1.y;
            acc[1][6] += av1 * w1.z; acc[1][7] += av1 * w1.w;
        }
    }

    if (MODE == 2) {
        float b[8];
        #pragma unroll
        for (int c = 0; c < 8; c++) b[c] = bias[c0 + c];
        #pragma unroll
        for (int r = 0; r < 2; r++) {
            int n = n0 + r0 + r;
            if (n >= N) continue;
            float4 o0 = make_float4(acc[r][0] + b[0], acc[r][1] + b[1],
                                    acc[r][2] + b[2], acc[r][3] + b[3]);
            float4 o1 = make_float4(acc[r][4] + b[4], acc[r][5] + b[5],
                                    acc[r][6] + b[6], acc[r][7] + b[7]);
            reinterpret_cast<float4*>(C)[(size_t)n * 32 + tx * 2] = o0;
            reinterpret_cast<float4*>(C)[(size_t)n * 32 + tx * 2 + 1] = o1;
        }
    } else {
        float ats[8], atd[8];
        #pragma unroll
        for (int c = 0; c < 8; c++) { ats[c] = att_s[c0 + c]; atd[c] = att_d[c0 + c]; }
        #pragma unroll
        for (int r = 0; r < 2; r++) {
            int n = n0 + r0 + r;
            union { uint4 v; unsigned short s[8]; } pk;
            #pragma unroll
            for (int c = 0; c < 8; c++) {
                __hip_bfloat16 hb = __float2bfloat16(acc[r][c]);
                pk.s[c] = *reinterpret_cast<unsigned short*>(&hb);
            }
            float ps = 0.f, pd = 0.f;
            #pragma unroll
            for (int c = 0; c < 8; c++) { ps += acc[r][c] * ats[c]; pd += acc[r][c] * atd[c]; }
            ps += __shfl_xor(ps, 1); ps += __shfl_xor(ps, 2);
            pd += __shfl_xor(pd, 1); pd += __shfl_xor(pd, 2);
            if (n < N) {
                *reinterpret_cast<uint4*>(xhb + (size_t)n * D + c0) = pk.v;
                if ((tx & 3) == 0) {
                    a_s[n * H + (tx >> 2)] = ps;
                    a_d[n * H + (tx >> 2)] = pd;
                }
            }
        }
    }
}

// ---------- fused GAT aggregate + bias + LN (+ReLU) + residual ----------
// One wave per node, 4 nodes per block. SINGLE PASS: no segment-max
// (lrelu-bounded logits make exp() safe in f32), no LDS, unnormalized
// accumulate + one divide. Lane layout: cl = lane&15 owns channels
// 8*cl..8*cl+7 (head hb = cl>>2); sub = lane>>4 picks 1 of 4 edges in flight.
__global__ __launch_bounds__(256) void k_gat5(
        const __hip_bfloat16* __restrict__ xhb, const int* __restrict__ off,
        const int2* __restrict__ adj2, const float* __restrict__ a_s,
        const float* __restrict__ a_d, const float* __restrict__ bias,
        const float* __restrict__ g, const float* __restrict__ bln,
        float* __restrict__ h, int N, int do_relu) {
    int wid = threadIdx.x >> 6;
    int lane = threadIdx.x & 63;
    int n = blockIdx.x * 4 + wid;
    if (n >= N) return;

    int cl = lane & 15;             // channel group: c0 = 8*cl
    int sub = lane >> 4;            // edge sub-slot (4 edges in flight)
    int hb = cl >> 2;               // head of this lane's channels
    int c0 = cl * 8;

    int beg = off[n], end = off[n + 1];
    int deg = end - beg;
    int items = deg + 1;            // + self loop
    int itp = (items + 3) & ~3;     // padded trip count (uniform across wave)

    float adA = a_d[n * H + hb];
    float den = 0.f;
    float acc[8];
    #pragma unroll
    for (int c = 0; c < 8; c++) acc[c] = 0.f;

    #pragma unroll 4
    for (int pp = sub; pp < itp; pp += 4) {
        int s = (pp < deg) ? adj2[beg + pp].x : n;     // self-loop / pad -> n
        float av = a_s[(size_t)s * H + hb];
        uint4 u = *reinterpret_cast<const uint4*>(xhb + (size_t)s * D + c0);
        float e = lrelu(av + adA);
        float wv = (pp < items) ? __expf(e) : 0.f;     // pad lanes contribute 0
        den += wv;
        float f;
        f = __uint_as_float(u.x << 16);         acc[0] += wv * f;
        f = __uint_as_float(u.x & 0xffff0000u); acc[1] += wv * f;
        f = __uint_as_float(u.y << 16);         acc[2] += wv * f;
        f = __uint_as_float(u.y & 0xffff0000u); acc[3] += wv * f;
        f = __uint_as_float(u.z << 16);         acc[4] += wv * f;
        f = __uint_as_float(u.z & 0xffff0000u); acc[5] += wv * f;
        f = __uint_as_float(u.w << 16);         acc[6] += wv * f;
        f = __uint_as_float(u.w & 0xffff0000u); acc[7] += wv * f;
    }

    // combine the 4 edge sub-slots (lanes cl, cl+16, cl+32, cl+48)
    #pragma unroll
    for (int c = 0; c < 8; c++) {
        acc[c] += __shfl_xor(acc[c], 16);
        acc[c] += __shfl_xor(acc[c], 32);
    }
    den += __shfl_xor(den, 16);
    den += __shfl_xor(den, 32);
    float rden = 1.0f / den;

    float4 b0 = *reinterpret_cast<const float4*>(bias + c0);
    float4 b1 = *reinterpret_cast<const float4*>(bias + c0 + 4);
    float o[8];
    o[0] = acc[0] * rden + b0.x; o[1] = acc[1] * rden + b0.y;
    o[2] = acc[2] * rden + b0.z; o[3] = acc[3] * rden + b0.w;
    o[4] = acc[4] * rden + b1.x; o[5] = acc[5] * rden + b1.y;
    o[6] = acc[6] * rden + b1.z; o[7] = acc[7] * rden + b1.w;

    // LayerNorm (each channel appears 4x across the wave -> divide by 512)
    float s1 = 0.f;
    #pragma unroll
    for (int c = 0; c < 8; c++) s1 += o[c];
    #pragma unroll
    for (int os = 1; os < 64; os <<= 1) s1 += __shfl_xor(s1, os);
    float mu = s1 * (1.0f / 512.0f);
    float s2 = 0.f;
    #pragma unroll
    for (int c = 0; c < 8; c++) { float dv = o[c] - mu; s2 += dv * dv; }
    #pragma unroll
    for (int os = 1; os < 64; os <<= 1) s2 += __shfl_xor(s2, os);
    float inv = rsqrtf(s2 * (1.0f / 512.0f) + LN_EPS);

    if (sub == 0) {
        float4 g0 = *reinterpret_cast<const float4*>(g + c0);
        float4 g1 = *reinterpret_cast<const float4*>(g + c0 + 4);
        float4 l0 = *reinterpret_cast<const float4*>(bln + c0);
        float4 l1 = *reinterpret_cast<const float4*>(bln + c0 + 4);
        float y[8];
        y[0] = (o[0] - mu) * inv * g0.x + l0.x;
        y[1] = (o[1] - mu) * inv * g0.y + l0.y;
        y[2] = (o[2] - mu) * inv * g0.z + l0.z;
        y[3] = (o[3] - mu) * inv * g0.w + l0.w;
        y[4] = (o[4] - mu) * inv * g1.x + l1.x;
        y[5] = (o[5] - mu) * inv * g1.y + l1.y;
        y[6] = (o[6] - mu) * inv * g1.z + l1.z;
        y[7] = (o[7] - mu) * inv * g1.w + l1.w;
        if (do_relu) {
            #pragma unroll
            for (int c = 0; c < 8; c++) y[c] = fmaxf(y[c], 0.f);
        }
        float4 h0 = *reinterpret_cast<float4*>(h + (size_t)n * D + c0);
        float4 h1 = *reinterpret_cast<float4*>(h + (size_t)n * D + c0 + 4);
        h0.x += y[0]; h0.y += y[1]; h0.z += y[2]; h0.w += y[3];
        h1.x += y[4]; h1.y += y[5]; h1.z += y[6]; h1.w += y[7];
        *reinterpret_cast<float4*>(h + (size_t)n * D + c0) = h0;
        *reinterpret_cast<float4*>(h + (size_t)n * D + c0 + 4) = h1;
    }
}

extern "C" void kernel_launch(void* const* d_in, const int* in_sizes, int n_in,
                              void* d_out, int out_size, void* d_ws, size_t ws_size,
                              hipStream_t stream) {
    const float* x       = (const float*)d_in[0];
    const int*   ei      = (const int*)  d_in[1];
    const float* W_edge  = (const float*)d_in[2];
    const float* b_edge  = (const float*)d_in[3];
    const float* W_node  = (const float*)d_in[4];
    const float* b_node  = (const float*)d_in[5];
    const float* lin_w   = (const float*)d_in[6];
    const float* att_src = (const float*)d_in[7];
    const float* att_dst = (const float*)d_in[8];
    const float* gat_b   = (const float*)d_in[9];
    const float* ln_g    = (const float*)d_in[10];
    const float* ln_b    = (const float*)d_in[11];

    int N = out_size / D;
    int E = in_sizes[1] / 2;
    int NB = (N + 255) / 256;

    char* w = (char*)d_ws;
    auto carve = [&](size_t bytes) {
        void* p = (void*)w;
        w += (bytes + 255) & ~(size_t)255;
        return p;
    };
    int*   cnt  = (int*)  carve((size_t)N * 4);
    int*   pos  = (int*)  carve((size_t)N * 4);
    int*   off  = (int*)  carve((size_t)(N + 1) * 4);
    int2*  adj2 = (int2*) carve((size_t)E * 8);
    int*   bsum = (int*)  carve((size_t)NB * 4);
    float* tmp  = (float*)carve((size_t)N * D * 4);
    float* a_s  = (float*)carve((size_t)N * H * 4);
    float* a_d  = (float*)carve((size_t)N * H * 4);
    __hip_bfloat16* xhb = (__hip_bfloat16*)tmp;

    float* h = (float*)d_out;

    hipMemsetAsync(cnt, 0, (size_t)N * 4, stream);
    hipMemsetAsync(pos, 0, (size_t)N * 4, stream);

    int tb = 256;
    k_count<<<(E + tb - 1) / tb, tb, 0, stream>>>(ei, cnt, E);
    k_scan_part<<<NB, 256, 0, stream>>>(cnt, off, bsum, N);
    k_scan_top<<<1, 256, 0, stream>>>(bsum, off, NB, N);
    k_scan_add<<<NB, 256, 0, stream>>>(cnt, off, bsum, N);
    k_fill<<<(E + tb - 1) / tb, tb, 0, stream>>>(ei, off, pos, adj2, E);
    k_gemm<2><<<(N + 31) / 32, 256, 0, stream>>>(
        nullptr, W_node, b_node, h, nullptr, nullptr, nullptr, nullptr, nullptr,
        x, adj2, off, W_edge, b_edge, N);

    for (int i = 0; i < 3; i++) {
        k_gemm<1><<<(N + 31) / 32, 256, 0, stream>>>(
            h, lin_w + (size_t)i * D * D, nullptr, nullptr,
            xhb, a_s, a_d, att_src + i * D, att_dst + i * D,
            nullptr, nullptr, nullptr, nullptr, nullptr, N);
        k_gat5<<<(N + 3) / 4, 256, 0, stream>>>(
            xhb, off, adj2, a_s, a_d,
            gat_b + i * D, ln_g + i * D, ln_b + i * D,
            h, N, (i < 2) ? 1 : 0);
    }
}

// Round 8
// 373.452 us; speedup vs baseline: 1.1576x; 1.1576x over previous
//
#include <hip/hip_runtime.h>
#include <hip/hip_bf16.h>
#include <math.h>

#define D 128
#define H 4
#define NEG_SLOPE 0.2f
#define LN_EPS 1e-5f

__device__ __forceinline__ float lrelu(float v) {
    return v > 0.f ? v : NEG_SLOPE * v;
}

// ---------- per-destination in-degree histogram (int atomics only) ----------
__global__ void k_count(const int* __restrict__ ei, int* __restrict__ cnt, int E) {
    int e = blockIdx.x * blockDim.x + threadIdx.x;
    if (e >= E) return;
    atomicAdd(&cnt[ei[E + e]], 1);
}

// ---------- hierarchical exclusive scan of cnt[N] -> off[N+1] ----------
__global__ void k_scan_part(const int* __restrict__ cnt, int* __restrict__ off,
                            int* __restrict__ bsum, int N) {
    __shared__ int sm[256];
    int i = blockIdx.x * 256 + threadIdx.x;
    int v = (i < N) ? cnt[i] : 0;
    sm[threadIdx.x] = v;
    __syncthreads();
    #pragma unroll
    for (int o = 1; o < 256; o <<= 1) {
        int t = (threadIdx.x >= (unsigned)o) ? sm[threadIdx.x - o] : 0;
        __syncthreads();
        sm[threadIdx.x] += t;
        __syncthreads();
    }
    if (i < N) off[i] = sm[threadIdx.x];
    if (threadIdx.x == 255) bsum[blockIdx.x] = sm[255];
}

__global__ void k_scan_top(int* __restrict__ bsum, int* __restrict__ off,
                           int NB, int N) {
    __shared__ int sm[256];
    int v = (threadIdx.x < (unsigned)NB) ? bsum[threadIdx.x] : 0;
    sm[threadIdx.x] = v;
    __syncthreads();
    #pragma unroll
    for (int o = 1; o < 256; o <<= 1) {
        int t = (threadIdx.x >= (unsigned)o) ? sm[threadIdx.x - o] : 0;
        __syncthreads();
        sm[threadIdx.x] += t;
        __syncthreads();
    }
    if (threadIdx.x < (unsigned)NB) bsum[threadIdx.x] = sm[threadIdx.x] - v;
    if (threadIdx.x == 255) off[N] = sm[255];
}

__global__ void k_scan_add(const int* __restrict__ cnt, int* __restrict__ off,
                           const int* __restrict__ bsum, int N) {
    int i = blockIdx.x * 256 + threadIdx.x;
    if (i < N) off[i] = off[i] - cnt[i] + bsum[blockIdx.x];
}

// ---------- CSR fill: adj2[slot] = {src, edge_id} (one 8B store) ----------
__global__ void k_fill(const int* __restrict__ ei, const int* __restrict__ off,
                       int* __restrict__ pos, int2* __restrict__ adj2, int E) {
    int e = blockIdx.x * blockDim.x + threadIdx.x;
    if (e >= E) return;
    int dst = ei[E + e];
    int slot = off[dst] + atomicAdd(&pos[dst], 1);
    adj2[slot] = make_int2(ei[e], e);
}

// ---------- GEMM: C[N,128] = A[N,128] @ W[128,128] ----------
// 64 rows x 128 cols per 256-thread block; 4x8 register tile per thread.
// BOTH operands from LDS: A tile [64][132] + W k-panel [32][132], panel
// single-buffered with register prefetch of the next panel (4 panels).
// MODE 1: A explicit, bf16 out + fused attention dots.
// MODE 2: A synthesized from scatter-mean (x gathered via CSR, W_edge, b_edge),
//         f32 out + bias.
template <int MODE>
__global__ __launch_bounds__(256) void k_gemm(
        const float* __restrict__ A, const float* __restrict__ W,
        const float* __restrict__ bias, float* __restrict__ C,
        __hip_bfloat16* __restrict__ xhb, float* __restrict__ a_s,
        float* __restrict__ a_d, const float* __restrict__ att_s,
        const float* __restrict__ att_d,
        const float* __restrict__ x, const int2* __restrict__ adj2,
        const int* __restrict__ off,
        const float* __restrict__ W_edge, const float* __restrict__ b_edge,
        int N) {
    __shared__ float As[64][132];
    __shared__ float Ws[32][132];
    int tid = threadIdx.x;
    int n0 = blockIdx.x * 64;

    if (MODE == 2) {
        __shared__ float rowf[64][4];
        // gather-sum raw 3-dim edge features: 4 threads per row
        {
            int r = tid >> 2, t4 = tid & 3;
            int n = n0 + r;
            float s0 = 0.f, s1 = 0.f, s2 = 0.f;
            int degv = 0;
            if (n < N) {
                int beg = off[n], end = off[n + 1];
                degv = end - beg;
                for (int p = beg + t4; p < end; p += 4) {
                    const float* xr = x + (size_t)adj2[p].y * 3;
                    s0 += xr[0]; s1 += xr[1]; s2 += xr[2];
                }
            }
            s0 += __shfl_xor(s0, 1); s0 += __shfl_xor(s0, 2);
            s1 += __shfl_xor(s1, 1); s1 += __shfl_xor(s1, 2);
            s2 += __shfl_xor(s2, 1); s2 += __shfl_xor(s2, 2);
            if (t4 == 0)
                *reinterpret_cast<float4*>(rowf[r]) =
                    make_float4(s0, s1, s2, (float)degv);
        }
        __syncthreads();
        int d = tid & 127;
        float we0 = W_edge[d], we1 = W_edge[D + d], we2 = W_edge[2 * D + d];
        float be = b_edge[d];
        for (int r = tid >> 7; r < 64; r += 2) {
            float4 rv = *reinterpret_cast<float4*>(rowf[r]);
            float c = rv.w;
            As[r][d] = (rv.x * we0 + rv.y * we1 + rv.z * we2 + c * be)
                       / fmaxf(c, 1.f);
        }
    } else {
        // stage 64 rows x 128 cols via float4: 2048 float4s, 8 per thread
        #pragma unroll
        for (int j = 0; j < 8; j++) {
            int i = tid + j * 256;
            int r = i >> 5, q = i & 31;
            int n = n0 + r;
            float4 v = make_float4(0.f, 0.f, 0.f, 0.f);
            if (n < N) v = reinterpret_cast<const float4*>(A)[(size_t)n * 32 + q];
            *reinterpret_cast<float4*>(&As[r][q * 4]) = v;
        }
    }

    // prefetch W panel 0 into registers (panel = 32 k-rows x 128 cols)
    const float4* Wv = reinterpret_cast<const float4*>(W);
    float4 pf[4];
    #pragma unroll
    for (int j = 0; j < 4; j++) {
        int idx = tid + j * 256;
        pf[j] = Wv[(idx >> 5) * 32 + (idx & 31)];
    }
    __syncthreads();     // As (and rowf consumers) complete

    int tx = tid & 15, ty = tid >> 4;
    int c0 = tx * 8, r0 = ty * 4;
    float acc[4][8];
    #pragma unroll
    for (int r = 0; r < 4; r++)
        #pragma unroll
        for (int c = 0; c < 8; c++) acc[r][c] = 0.f;

    for (int p = 0; p < 4; p++) {
        // store current panel to LDS
        #pragma unroll
        for (int j = 0; j < 4; j++) {
            int idx = tid + j * 256;
            *reinterpret_cast<float4*>(&Ws[idx >> 5][(idx & 31) * 4]) = pf[j];
        }
        __syncthreads();
        // prefetch next panel
        if (p < 3) {
            #pragma unroll
            for (int j = 0; j < 4; j++) {
                int idx = tid + j * 256;
                pf[j] = Wv[((p + 1) * 32 + (idx >> 5)) * 32 + (idx & 31)];
            }
        }
        // compute 32 k's from LDS
        #pragma unroll 4
        for (int kk4 = 0; kk4 < 8; kk4++) {
            int kc = p * 32 + kk4 * 4;
            float4 a0 = *reinterpret_cast<const float4*>(&As[r0 + 0][kc]);
            float4 a1 = *reinterpret_cast<const float4*>(&As[r0 + 1][kc]);
            float4 a2 = *reinterpret_cast<const float4*>(&As[r0 + 2][kc]);
            float4 a3 = *reinterpret_cast<const float4*>(&As[r0 + 3][kc]);
            #pragma unroll
            for (int j = 0; j < 4; j++) {
                float4 w0 = *reinterpret_cast<const float4*>(&Ws[kk4 * 4 + j][c0]);
                float4 w1 = *reinterpret_cast<const float4*>(&Ws[kk4 * 4 + j][c0 + 4]);
                float av;
                av = (&a0.x)[j];
                acc[0][0] += av * w0.x; acc[0][1] += av * w0.y;
                acc[0][2] += av * w0.z; acc[0][3] += av * w0.w;
                acc[0][4] += av * w1.x; acc[0][5] += av * w1.y;
                acc[0][6] += av * w1.z; acc[0][7] += av * w1.w;
                av = (&a1.x)[j];
                acc[1][0] += av * w0.x; acc[1][1] += av * w0.y;
                acc[1][2] += av * w0.z; acc[1][3] += av * w0.w;
                acc[1][4] += av * w1.x; acc[1][5] += av * w1.y;
                acc[1][6] += av * w1.z; acc[1][7] += av * w1.w;
                av = (&a2.x)[j];
                acc[2][0] += av * w0.x; acc[2][1] += av * w0.y;
                acc[2][2] += av * w0.z; acc[2][3] += av * w0.w;
                acc[2][4] += av * w1.x; acc[2][5] += av * w1.y;
                acc[2][6] += av * w1.z; acc[2][7] += av * w1.w;
                av = (&a3.x)[j];
                acc[3][0] += av * w0.x; acc[3][1] += av * w0.y;
                acc[3][2] += av * w0.z; acc[3][3] += av * w0.w;
                acc[3][4] += av * w1.x; acc[3][5] += av * w1.y;
                acc[3][6] += av * w1.z; acc[3][7] += av * w1.w;
            }
        }
        __syncthreads();   // done reading Ws before next overwrite
    }

    if (MODE == 2) {
        float b[8];
        #pragma unroll
        for (int c = 0; c < 8; c++) b[c] = bias[c0 + c];
        #pragma unroll
        for (int r = 0; r < 4; r++) {
            int n = n0 + r0 + r;
            if (n >= N) continue;
            float4 o0 = make_float4(acc[r][0] + b[0], acc[r][1] + b[1],
                                    acc[r][2] + b[2], acc[r][3] + b[3]);
            float4 o1 = make_float4(acc[r][4] + b[4], acc[r][5] + b[5],
                                    acc[r][6] + b[6], acc[r][7] + b[7]);
            reinterpret_cast<float4*>(C)[(size_t)n * 32 + tx * 2] = o0;
            reinterpret_cast<float4*>(C)[(size_t)n * 32 + tx * 2 + 1] = o1;
        }
    } else {
        float ats[8], atd[8];
        #pragma unroll
        for (int c = 0; c < 8; c++) { ats[c] = att_s[c0 + c]; atd[c] = att_d[c0 + c]; }
        #pragma unroll
        for (int r = 0; r < 4; r++) {
            int n = n0 + r0 + r;
            union { uint4 v; unsigned short s[8]; } pk;
            #pragma unroll
            for (int c = 0; c < 8; c++) {
                __hip_bfloat16 hb = __float2bfloat16(acc[r][c]);
                pk.s[c] = *reinterpret_cast<unsigned short*>(&hb);
            }
            float ps = 0.f, pd = 0.f;
            #pragma unroll
            for (int c = 0; c < 8; c++) { ps += acc[r][c] * ats[c]; pd += acc[r][c] * atd[c]; }
            ps += __shfl_xor(ps, 1); ps += __shfl_xor(ps, 2);
            pd += __shfl_xor(pd, 1); pd += __shfl_xor(pd, 2);
            if (n < N) {
                *reinterpret_cast<uint4*>(xhb + (size_t)n * D + c0) = pk.v;
                if ((tx & 3) == 0) {
                    a_s[n * H + (tx >> 2)] = ps;
                    a_d[n * H + (tx >> 2)] = pd;
                }
            }
        }
    }
}

// ---------- fused GAT aggregate + bias + LN (+ReLU) + residual ----------
// One wave per node, 4 nodes per block. SINGLE PASS: no segment-max
// (lrelu-bounded logits make exp() safe in f32), no LDS, unnormalized
// accumulate + one divide. Lane layout: cl = lane&15 owns channels
// 8*cl..8*cl+7 (head hb = cl>>2); sub = lane>>4 picks 1 of 4 edges in flight.
__global__ __launch_bounds__(256) void k_gat5(
        const __hip_bfloat16* __restrict__ xhb, const int* __restrict__ off,
        const int2* __restrict__ adj2, const float* __restrict__ a_s,
        const float* __restrict__ a_d, const float* __restrict__ bias,
        const float* __restrict__ g, const float* __restrict__ bln,
        float* __restrict__ h, int N, int do_relu) {
    int wid = threadIdx.x >> 6;
    int lane = threadIdx.x & 63;
    int n = blockIdx.x * 4 + wid;
    if (n >= N) return;

    int cl = lane & 15;             // channel group: c0 = 8*cl
    int sub = lane >> 4;            // edge sub-slot (4 edges in flight)
    int hb = cl >> 2;               // head of this lane's channels
    int c0 = cl * 8;

    int beg = off[n], end = off[n + 1];
    int deg = end - beg;
    int items = deg + 1;            // + self loop
    int itp = (items + 3) & ~3;     // padded trip count (uniform across wave)

    float adA = a_d[n * H + hb];
    float den = 0.f;
    float acc[8];
    #pragma unroll
    for (int c = 0; c < 8; c++) acc[c] = 0.f;

    #pragma unroll 4
    for (int pp = sub; pp < itp; pp += 4) {
        int s = (pp < deg) ? adj2[beg + pp].x : n;     // self-loop / pad -> n
        float av = a_s[(size_t)s * H + hb];
        uint4 u = *reinterpret_cast<const uint4*>(xhb + (size_t)s * D + c0);
        float e = lrelu(av + adA);
        float wv = (pp < items) ? __expf(e) : 0.f;     // pad lanes contribute 0
        den += wv;
        float f;
        f = __uint_as_float(u.x << 16);         acc[0] += wv * f;
        f = __uint_as_float(u.x & 0xffff0000u); acc[1] += wv * f;
        f = __uint_as_float(u.y << 16);         acc[2] += wv * f;
        f = __uint_as_float(u.y & 0xffff0000u); acc[3] += wv * f;
        f = __uint_as_float(u.z << 16);         acc[4] += wv * f;
        f = __uint_as_float(u.z & 0xffff0000u); acc[5] += wv * f;
        f = __uint_as_float(u.w << 16);         acc[6] += wv * f;
        f = __uint_as_float(u.w & 0xffff0000u); acc[7] += wv * f;
    }

    // combine the 4 edge sub-slots (lanes cl, cl+16, cl+32, cl+48)
    #pragma unroll
    for (int c = 0; c < 8; c++) {
        acc[c] += __shfl_xor(acc[c], 16);
        acc[c] += __shfl_xor(acc[c], 32);
    }
    den += __shfl_xor(den, 16);
    den += __shfl_xor(den, 32);
    float rden = 1.0f / den;

    float4 b0 = *reinterpret_cast<const float4*>(bias + c0);
    float4 b1 = *reinterpret_cast<const float4*>(bias + c0 + 4);
    float o[8];
    o[0] = acc[0] * rden + b0.x; o[1] = acc[1] * rden + b0.y;
    o[2] = acc[2] * rden + b0.z; o[3] = acc[3] * rden + b0.w;
    o[4] = acc[4] * rden + b1.x; o[5] = acc[5] * rden + b1.y;
    o[6] = acc[6] * rden + b1.z; o[7] = acc[7] * rden + b1.w;

    // LayerNorm (each channel appears 4x across the wave -> divide by 512)
    float s1 = 0.f;
    #pragma unroll
    for (int c = 0; c < 8; c++) s1 += o[c];
    #pragma unroll
    for (int os = 1; os < 64; os <<= 1) s1 += __shfl_xor(s1, os);
    float mu = s1 * (1.0f / 512.0f);
    float s2 = 0.f;
    #pragma unroll
    for (int c = 0; c < 8; c++) { float dv = o[c] - mu; s2 += dv * dv; }
    #pragma unroll
    for (int os = 1; os < 64; os <<= 1) s2 += __shfl_xor(s2, os);
    float inv = rsqrtf(s2 * (1.0f / 512.0f) + LN_EPS);

    if (sub == 0) {
        float4 g0 = *reinterpret_cast<const float4*>(g + c0);
        float4 g1 = *reinterpret_cast<const float4*>(g + c0 + 4);
        float4 l0 = *reinterpret_cast<const float4*>(bln + c0);
        float4 l1 = *reinterpret_cast<const float4*>(bln + c0 + 4);
        float y[8];
        y[0] = (o[0] - mu) * inv * g0.x + l0.x;
        y[1] = (o[1] - mu) * inv * g0.y + l0.y;
        y[2] = (o[2] - mu) * inv * g0.z + l0.z;
        y[3] = (o[3] - mu) * inv * g0.w + l0.w;
        y[4] = (o[4] - mu) * inv * g1.x + l1.x;
        y[5] = (o[5] - mu) * inv * g1.y + l1.y;
        y[6] = (o[6] - mu) * inv * g1.z + l1.z;
        y[7] = (o[7] - mu) * inv * g1.w + l1.w;
        if (do_relu) {
            #pragma unroll
            for (int c = 0; c < 8; c++) y[c] = fmaxf(y[c], 0.f);
        }
        float4 h0 = *reinterpret_cast<float4*>(h + (size_t)n * D + c0);
        float4 h1 = *reinterpret_cast<float4*>(h + (size_t)n * D + c0 + 4);
        h0.x += y[0]; h0.y += y[1]; h0.z += y[2]; h0.w += y[3];
        h1.x += y[4]; h1.y += y[5]; h1.z += y[6]; h1.w += y[7];
        *reinterpret_cast<float4*>(h + (size_t)n * D + c0) = h0;
        *reinterpret_cast<float4*>(h + (size_t)n * D + c0 + 4) = h1;
    }
}

extern "C" void kernel_launch(void* const* d_in, const int* in_sizes, int n_in,
                              void* d_out, int out_size, void* d_ws, size_t ws_size,
                              hipStream_t stream) {
    const float* x       = (const float*)d_in[0];
    const int*   ei      = (const int*)  d_in[1];
    const float* W_edge  = (const float*)d_in[2];
    const float* b_edge  = (const float*)d_in[3];
    const float* W_node  = (const float*)d_in[4];
    const float* b_node  = (const float*)d_in[5];
    const float* lin_w   = (const float*)d_in[6];
    const float* att_src = (const float*)d_in[7];
    const float* att_dst = (const float*)d_in[8];
    const float* gat_b   = (const float*)d_in[9];
    const float* ln_g    = (const float*)d_in[10];
    const float* ln_b    = (const float*)d_in[11];

    int N = out_size / D;
    int E = in_sizes[1] / 2;
    int NB = (N + 255) / 256;

    char* w = (char*)d_ws;
    auto carve = [&](size_t bytes) {
        void* p = (void*)w;
        w += (bytes + 255) & ~(size_t)255;
        return p;
    };
    int*   cnt  = (int*)  carve((size_t)N * 4);
    int*   pos  = (int*)  carve((size_t)N * 4);
    int*   off  = (int*)  carve((size_t)(N + 1) * 4);
    int2*  adj2 = (int2*) carve((size_t)E * 8);
    int*   bsum = (int*)  carve((size_t)NB * 4);
    float* tmp  = (float*)carve((size_t)N * D * 4);
    float* a_s  = (float*)carve((size_t)N * H * 4);
    float* a_d  = (float*)carve((size_t)N * H * 4);
    __hip_bfloat16* xhb = (__hip_bfloat16*)tmp;

    float* h = (float*)d_out;

    hipMemsetAsync(cnt, 0, (size_t)N * 4, stream);
    hipMemsetAsync(pos, 0, (size_t)N * 4, stream);

    int tb = 256;
    k_count<<<(E + tb - 1) / tb, tb, 0, stream>>>(ei, cnt, E);
    k_scan_part<<<NB, 256, 0, stream>>>(cnt, off, bsum, N);
    k_scan_top<<<1, 256, 0, stream>>>(bsum, off, NB, N);
    k_scan_add<<<NB, 256, 0, stream>>>(cnt, off, bsum, N);
    k_fill<<<(E + tb - 1) / tb, tb, 0, stream>>>(ei, off, pos, adj2, E);
    k_gemm<2><<<(N + 63) / 64, 256, 0, stream>>>(
        nullptr, W_node, b_node, h, nullptr, nullptr, nullptr, nullptr, nullptr,
        x, adj2, off, W_edge, b_edge, N);

    for (int i = 0; i < 3; i++) {
        k_gemm<1><<<(N + 63) / 64, 256, 0, stream>>>(
            h, lin_w + (size_t)i * D * D, nullptr, nullptr,
            xhb, a_s, a_d, att_src + i * D, att_dst + i * D,
            nullptr, nullptr, nullptr, nullptr, nullptr, N);
        k_gat5<<<(N + 3) / 4, 256, 0, stream>>>(
            xhb, off, adj2, a_s, a_d,
            gat_b + i * D, ln_g + i * D, ln_b + i * D,
            h, N, (i < 2) ? 1 : 0);
    }
}

// Round 9
// 365.034 us; speedup vs baseline: 1.1843x; 1.0231x over previous
//
#include <hip/hip_runtime.h>
#include <hip/hip_bf16.h>
#include <math.h>

#define D 128
#define H 4
#define NEG_SLOPE 0.2f
#define LN_EPS 1e-5f

__device__ __forceinline__ float lrelu(float v) {
    return v > 0.f ? v : NEG_SLOPE * v;
}

// ---------- per-destination in-degree histogram (int atomics only) ----------
__global__ void k_count(const int* __restrict__ ei, int* __restrict__ cnt, int E) {
    int e = blockIdx.x * blockDim.x + threadIdx.x;
    if (e >= E) return;
    atomicAdd(&cnt[ei[E + e]], 1);
}

// ---------- hierarchical exclusive scan of cnt[N] -> off[N+1] ----------
__global__ void k_scan_part(const int* __restrict__ cnt, int* __restrict__ off,
                            int* __restrict__ bsum, int N) {
    __shared__ int sm[256];
    int i = blockIdx.x * 256 + threadIdx.x;
    int v = (i < N) ? cnt[i] : 0;
    sm[threadIdx.x] = v;
    __syncthreads();
    #pragma unroll
    for (int o = 1; o < 256; o <<= 1) {
        int t = (threadIdx.x >= (unsigned)o) ? sm[threadIdx.x - o] : 0;
        __syncthreads();
        sm[threadIdx.x] += t;
        __syncthreads();
    }
    if (i < N) off[i] = sm[threadIdx.x];
    if (threadIdx.x == 255) bsum[blockIdx.x] = sm[255];
}

__global__ void k_scan_top(int* __restrict__ bsum, int* __restrict__ off,
                           int NB, int N) {
    __shared__ int sm[256];
    int v = (threadIdx.x < (unsigned)NB) ? bsum[threadIdx.x] : 0;
    sm[threadIdx.x] = v;
    __syncthreads();
    #pragma unroll
    for (int o = 1; o < 256; o <<= 1) {
        int t = (threadIdx.x >= (unsigned)o) ? sm[threadIdx.x - o] : 0;
        __syncthreads();
        sm[threadIdx.x] += t;
        __syncthreads();
    }
    if (threadIdx.x < (unsigned)NB) bsum[threadIdx.x] = sm[threadIdx.x] - v;
    if (threadIdx.x == 255) off[N] = sm[255];
}

__global__ void k_scan_add(const int* __restrict__ cnt, int* __restrict__ off,
                           const int* __restrict__ bsum, int N) {
    int i = blockIdx.x * 256 + threadIdx.x;
    if (i < N) off[i] = off[i] - cnt[i] + bsum[blockIdx.x];
}

// ---------- CSR fill: adj2[slot] = {src, edge_id} (one 8B store) ----------
__global__ void k_fill(const int* __restrict__ ei, const int* __restrict__ off,
                       int* __restrict__ pos, int2* __restrict__ adj2, int E) {
    int e = blockIdx.x * blockDim.x + threadIdx.x;
    if (e >= E) return;
    int dst = ei[E + e];
    int slot = off[dst] + atomicAdd(&pos[dst], 1);
    adj2[slot] = make_int2(ei[e], e);
}

// ---------- GEMM: C[N,128] = A[N,128] @ W[128,128] ----------
// 64 rows x 128 cols per 256-thread block; 4x8 register tile per thread.
// A in LDS [64][132]; W streamed from L2 with an explicit 2-deep register
// software pipeline (prefetch rows k+2,k+3 while computing k,k+1).
// MODE 1: A explicit, bf16 out + fused attention dots.
// MODE 2: A synthesized from scatter-mean (x gathered via CSR, W_edge, b_edge),
//         f32 out + bias.
template <int MODE>
__global__ __launch_bounds__(256) void k_gemm(
        const float* __restrict__ A, const float* __restrict__ W,
        const float* __restrict__ bias, float* __restrict__ C,
        __hip_bfloat16* __restrict__ xhb, float* __restrict__ a_s,
        float* __restrict__ a_d, const float* __restrict__ att_s,
        const float* __restrict__ att_d,
        const float* __restrict__ x, const int2* __restrict__ adj2,
        const int* __restrict__ off,
        const float* __restrict__ W_edge, const float* __restrict__ b_edge,
        int N) {
    __shared__ float As[64][132];
    int tid = threadIdx.x;
    int n0 = blockIdx.x * 64;

    if (MODE == 2) {
        __shared__ float rowf[64][4];
        // gather-sum raw 3-dim edge features: 4 threads per row
        {
            int r = tid >> 2, t4 = tid & 3;
            int n = n0 + r;
            float s0 = 0.f, s1 = 0.f, s2 = 0.f;
            int degv = 0;
            if (n < N) {
                int beg = off[n], end = off[n + 1];
                degv = end - beg;
                for (int p = beg + t4; p < end; p += 4) {
                    const float* xr = x + (size_t)adj2[p].y * 3;
                    s0 += xr[0]; s1 += xr[1]; s2 += xr[2];
                }
            }
            s0 += __shfl_xor(s0, 1); s0 += __shfl_xor(s0, 2);
            s1 += __shfl_xor(s1, 1); s1 += __shfl_xor(s1, 2);
            s2 += __shfl_xor(s2, 1); s2 += __shfl_xor(s2, 2);
            if (t4 == 0)
                *reinterpret_cast<float4*>(rowf[r]) =
                    make_float4(s0, s1, s2, (float)degv);
        }
        __syncthreads();
        int d = tid & 127;
        float we0 = W_edge[d], we1 = W_edge[D + d], we2 = W_edge[2 * D + d];
        float be = b_edge[d];
        for (int r = tid >> 7; r < 64; r += 2) {
            float4 rv = *reinterpret_cast<float4*>(rowf[r]);
            float c = rv.w;
            As[r][d] = (rv.x * we0 + rv.y * we1 + rv.z * we2 + c * be)
                       / fmaxf(c, 1.f);
        }
    } else {
        // stage 64 rows x 128 cols via float4: 2048 float4s, 8 per thread
        #pragma unroll
        for (int j = 0; j < 8; j++) {
            int i = tid + j * 256;
            int r = i >> 5, q = i & 31;
            int n = n0 + r;
            float4 v = make_float4(0.f, 0.f, 0.f, 0.f);
            if (n < N) v = reinterpret_cast<const float4*>(A)[(size_t)n * 32 + q];
            *reinterpret_cast<float4*>(&As[r][q * 4]) = v;
        }
    }
    __syncthreads();

    int tx = tid & 15, ty = tid >> 4;
    int c0 = tx * 8, r0 = ty * 4;
    float acc[4][8];
    #pragma unroll
    for (int r = 0; r < 4; r++)
        #pragma unroll
        for (int c = 0; c < 8; c++) acc[r][c] = 0.f;

    auto fma8 = [&](int rr, float av, const float4& w0, const float4& w1) {
        acc[rr][0] += av * w0.x; acc[rr][1] += av * w0.y;
        acc[rr][2] += av * w0.z; acc[rr][3] += av * w0.w;
        acc[rr][4] += av * w1.x; acc[rr][5] += av * w1.y;
        acc[rr][6] += av * w1.z; acc[rr][7] += av * w1.w;
    };

    const float4* Wv = reinterpret_cast<const float4*>(W);
    // software pipeline: hold W rows k,k+1; prefetch k+2,k+3 during compute
    float4 w0a = Wv[0 * 32 + tx * 2], w1a = Wv[0 * 32 + tx * 2 + 1];
    float4 w0b = Wv[1 * 32 + tx * 2], w1b = Wv[1 * 32 + tx * 2 + 1];
    #pragma unroll 2
    for (int k = 0; k < D; k += 2) {
        int kp = (k + 2) & 127;      // wraps at end; values unused
        int kq = (k + 3) & 127;
        float4 p0 = Wv[kp * 32 + tx * 2], p1 = Wv[kp * 32 + tx * 2 + 1];
        float4 q0 = Wv[kq * 32 + tx * 2], q1 = Wv[kq * 32 + tx * 2 + 1];
        float2 a0 = *reinterpret_cast<const float2*>(&As[r0 + 0][k]);
        float2 a1 = *reinterpret_cast<const float2*>(&As[r0 + 1][k]);
        float2 a2 = *reinterpret_cast<const float2*>(&As[r0 + 2][k]);
        float2 a3 = *reinterpret_cast<const float2*>(&As[r0 + 3][k]);
        fma8(0, a0.x, w0a, w1a); fma8(1, a1.x, w0a, w1a);
        fma8(2, a2.x, w0a, w1a); fma8(3, a3.x, w0a, w1a);
        fma8(0, a0.y, w0b, w1b); fma8(1, a1.y, w0b, w1b);
        fma8(2, a2.y, w0b, w1b); fma8(3, a3.y, w0b, w1b);
        w0a = p0; w1a = p1; w0b = q0; w1b = q1;
    }

    if (MODE == 2) {
        float b[8];
        #pragma unroll
        for (int c = 0; c < 8; c++) b[c] = bias[c0 + c];
        #pragma unroll
        for (int r = 0; r < 4; r++) {
            int n = n0 + r0 + r;
            if (n >= N) continue;
            float4 o0 = make_float4(acc[r][0] + b[0], acc[r][1] + b[1],
                                    acc[r][2] + b[2], acc[r][3] + b[3]);
            float4 o1 = make_float4(acc[r][4] + b[4], acc[r][5] + b[5],
                                    acc[r][6] + b[6], acc[r][7] + b[7]);
            reinterpret_cast<float4*>(C)[(size_t)n * 32 + tx * 2] = o0;
            reinterpret_cast<float4*>(C)[(size_t)n * 32 + tx * 2 + 1] = o1;
        }
    } else {
        float ats[8], atd[8];
        #pragma unroll
        for (int c = 0; c < 8; c++) { ats[c] = att_s[c0 + c]; atd[c] = att_d[c0 + c]; }
        #pragma unroll
        for (int r = 0; r < 4; r++) {
            int n = n0 + r0 + r;
            union { uint4 v; unsigned short s[8]; } pk;
            #pragma unroll
            for (int c = 0; c < 8; c++) {
                __hip_bfloat16 hb = __float2bfloat16(acc[r][c]);
                pk.s[c] = *reinterpret_cast<unsigned short*>(&hb);
            }
            float ps = 0.f, pd = 0.f;
            #pragma unroll
            for (int c = 0; c < 8; c++) { ps += acc[r][c] * ats[c]; pd += acc[r][c] * atd[c]; }
            ps += __shfl_xor(ps, 1); ps += __shfl_xor(ps, 2);
            pd += __shfl_xor(pd, 1); pd += __shfl_xor(pd, 2);
            if (n < N) {
                *reinterpret_cast<uint4*>(xhb + (size_t)n * D + c0) = pk.v;
                if ((tx & 3) == 0) {
                    a_s[n * H + (tx >> 2)] = ps;
                    a_d[n * H + (tx >> 2)] = pd;
                }
            }
        }
    }
}

// ---------- fused GAT aggregate + bias + LN (+ReLU) + residual ----------
// One wave per node, 16 nodes per 1024-thread block (fewer, longer-lived
// blocks -> no dispatch starvation). SINGLE PASS: no segment-max
// (lrelu-bounded logits make exp() safe in f32), no LDS. Lane layout:
// cl = lane&15 owns channels 8*cl..8*cl+7; sub = lane>>4 picks 1 of 4 edges.
__global__ __launch_bounds__(1024) void k_gat5(
        const __hip_bfloat16* __restrict__ xhb, const int* __restrict__ off,
        const int2* __restrict__ adj2, const float* __restrict__ a_s,
        const float* __restrict__ a_d, const float* __restrict__ bias,
        const float* __restrict__ g, const float* __restrict__ bln,
        float* __restrict__ h, int N, int do_relu) {
    int wid = threadIdx.x >> 6;
    int lane = threadIdx.x & 63;
    int n = blockIdx.x * 16 + wid;
    if (n >= N) return;

    int cl = lane & 15;             // channel group: c0 = 8*cl
    int sub = lane >> 4;            // edge sub-slot (4 edges in flight)
    int hb = cl >> 2;               // head of this lane's channels
    int c0 = cl * 8;

    int beg = off[n], end = off[n + 1];
    int deg = end - beg;
    int items = deg + 1;            // + self loop
    int itp = (items + 3) & ~3;     // padded trip count (uniform across wave)

    float adA = a_d[n * H + hb];
    float den = 0.f;
    float acc[8];
    #pragma unroll
    for (int c = 0; c < 8; c++) acc[c] = 0.f;

    #pragma unroll 4
    for (int pp = sub; pp < itp; pp += 4) {
        int s = (pp < deg) ? adj2[beg + pp].x : n;     // self-loop / pad -> n
        float av = a_s[(size_t)s * H + hb];
        uint4 u = *reinterpret_cast<const uint4*>(xhb + (size_t)s * D + c0);
        float e = lrelu(av + adA);
        float wv = (pp < items) ? __expf(e) : 0.f;     // pad lanes contribute 0
        den += wv;
        float f;
        f = __uint_as_float(u.x << 16);         acc[0] += wv * f;
        f = __uint_as_float(u.x & 0xffff0000u); acc[1] += wv * f;
        f = __uint_as_float(u.y << 16);         acc[2] += wv * f;
        f = __uint_as_float(u.y & 0xffff0000u); acc[3] += wv * f;
        f = __uint_as_float(u.z << 16);         acc[4] += wv * f;
        f = __uint_as_float(u.z & 0xffff0000u); acc[5] += wv * f;
        f = __uint_as_float(u.w << 16);         acc[6] += wv * f;
        f = __uint_as_float(u.w & 0xffff0000u); acc[7] += wv * f;
    }

    // combine the 4 edge sub-slots (lanes cl, cl+16, cl+32, cl+48)
    #pragma unroll
    for (int c = 0; c < 8; c++) {
        acc[c] += __shfl_xor(acc[c], 16);
        acc[c] += __shfl_xor(acc[c], 32);
    }
    den += __shfl_xor(den, 16);
    den += __shfl_xor(den, 32);
    float rden = 1.0f / den;

    float4 b0 = *reinterpret_cast<const float4*>(bias + c0);
    float4 b1 = *reinterpret_cast<const float4*>(bias + c0 + 4);
    float o[8];
    o[0] = acc[0] * rden + b0.x; o[1] = acc[1] * rden + b0.y;
    o[2] = acc[2] * rden + b0.z; o[3] = acc[3] * rden + b0.w;
    o[4] = acc[4] * rden + b1.x; o[5] = acc[5] * rden + b1.y;
    o[6] = acc[6] * rden + b1.z; o[7] = acc[7] * rden + b1.w;

    // LayerNorm (each channel appears 4x across the wave -> divide by 512)
    float s1 = 0.f;
    #pragma unroll
    for (int c = 0; c < 8; c++) s1 += o[c];
    #pragma unroll
    for (int os = 1; os < 64; os <<= 1) s1 += __shfl_xor(s1, os);
    float mu = s1 * (1.0f / 512.0f);
    float s2 = 0.f;
    #pragma unroll
    for (int c = 0; c < 8; c++) { float dv = o[c] - mu; s2 += dv * dv; }
    #pragma unroll
    for (int os = 1; os < 64; os <<= 1) s2 += __shfl_xor(s2, os);
    float inv = rsqrtf(s2 * (1.0f / 512.0f) + LN_EPS);

    if (sub == 0) {
        float4 g0 = *reinterpret_cast<const float4*>(g + c0);
        float4 g1 = *reinterpret_cast<const float4*>(g + c0 + 4);
        float4 l0 = *reinterpret_cast<const float4*>(bln + c0);
        float4 l1 = *reinterpret_cast<const float4*>(bln + c0 + 4);
        float y[8];
        y[0] = (o[0] - mu) * inv * g0.x + l0.x;
        y[1] = (o[1] - mu) * inv * g0.y + l0.y;
        y[2] = (o[2] - mu) * inv * g0.z + l0.z;
        y[3] = (o[3] - mu) * inv * g0.w + l0.w;
        y[4] = (o[4] - mu) * inv * g1.x + l1.x;
        y[5] = (o[5] - mu) * inv * g1.y + l1.y;
        y[6] = (o[6] - mu) * inv * g1.z + l1.z;
        y[7] = (o[7] - mu) * inv * g1.w + l1.w;
        if (do_relu) {
            #pragma unroll
            for (int c = 0; c < 8; c++) y[c] = fmaxf(y[c], 0.f);
        }
        float4 h0 = *reinterpret_cast<float4*>(h + (size_t)n * D + c0);
        float4 h1 = *reinterpret_cast<float4*>(h + (size_t)n * D + c0 + 4);
        h0.x += y[0]; h0.y += y[1]; h0.z += y[2]; h0.w += y[3];
        h1.x += y[4]; h1.y += y[5]; h1.z += y[6]; h1.w += y[7];
        *reinterpret_cast<float4*>(h + (size_t)n * D + c0) = h0;
        *reinterpret_cast<float4*>(h + (size_t)n * D + c0 + 4) = h1;
    }
}

extern "C" void kernel_launch(void* const* d_in, const int* in_sizes, int n_in,
                              void* d_out, int out_size, void* d_ws, size_t ws_size,
                              hipStream_t stream) {
    const float* x       = (const float*)d_in[0];
    const int*   ei      = (const int*)  d_in[1];
    const float* W_edge  = (const float*)d_in[2];
    const float* b_edge  = (const float*)d_in[3];
    const float* W_node  = (const float*)d_in[4];
    const float* b_node  = (const float*)d_in[5];
    const float* lin_w   = (const float*)d_in[6];
    const float* att_src = (const float*)d_in[7];
    const float* att_dst = (const float*)d_in[8];
    const float* gat_b   = (const float*)d_in[9];
    const float* ln_g    = (const float*)d_in[10];
    const float* ln_b    = (const float*)d_in[11];

    int N = out_size / D;
    int E = in_sizes[1] / 2;
    int NB = (N + 255) / 256;

    char* w = (char*)d_ws;
    auto carve = [&](size_t bytes) {
        void* p = (void*)w;
        w += (bytes + 255) & ~(size_t)255;
        return p;
    };
    int*   cnt  = (int*)  carve((size_t)N * 4);
    int*   pos  = (int*)  carve((size_t)N * 4);
    int*   off  = (int*)  carve((size_t)(N + 1) * 4);
    int2*  adj2 = (int2*) carve((size_t)E * 8);
    int*   bsum = (int*)  carve((size_t)NB * 4);
    float* tmp  = (float*)carve((size_t)N * D * 4);
    float* a_s  = (float*)carve((size_t)N * H * 4);
    float* a_d  = (float*)carve((size_t)N * H * 4);
    __hip_bfloat16* xhb = (__hip_bfloat16*)tmp;

    float* h = (float*)d_out;

    // cnt and pos are adjacent carves -> one memset covers both
    hipMemsetAsync(cnt, 0, (size_t)((char*)pos - (char*)cnt) + (size_t)N * 4, stream);

    int tb = 256;
    k_count<<<(E + tb - 1) / tb, tb, 0, stream>>>(ei, cnt, E);
    k_scan_part<<<NB, 256, 0, stream>>>(cnt, off, bsum, N);
    k_scan_top<<<1, 256, 0, stream>>>(bsum, off, NB, N);
    k_scan_add<<<NB, 256, 0, stream>>>(cnt, off, bsum, N);
    k_fill<<<(E + tb - 1) / tb, tb, 0, stream>>>(ei, off, pos, adj2, E);
    k_gemm<2><<<(N + 63) / 64, 256, 0, stream>>>(
        nullptr, W_node, b_node, h, nullptr, nullptr, nullptr, nullptr, nullptr,
        x, adj2, off, W_edge, b_edge, N);

    for (int i = 0; i < 3; i++) {
        k_gemm<1><<<(N + 63) / 64, 256, 0, stream>>>(
            h, lin_w + (size_t)i * D * D, nullptr, nullptr,
            xhb, a_s, a_d, att_src + i * D, att_dst + i * D,
            nullptr, nullptr, nullptr, nullptr, nullptr, N);
        k_gat5<<<(N + 15) / 16, 1024, 0, stream>>>(
            xhb, off, adj2, a_s, a_d,
            gat_b + i * D, ln_g + i * D, ln_b + i * D,
            h, N, (i < 2) ? 1 : 0);
    }
}

// Round 10
// 260.172 us; speedup vs baseline: 1.6616x; 1.4031x over previous
//
#include <hip/hip_runtime.h>
#include <hip/hip_bf16.h>
#include <math.h>

#define D 128
#define H 4
#define NEG_SLOPE 0.2f
#define LN_EPS 1e-5f
#define LDA 136    // bf16 elems per LDS row: 272 B = 17*16B -> conflict-free b128
#define LDE 132    // f32 epilogue LDS row stride: 528 B, 16B-aligned

using bf16x8 = __attribute__((ext_vector_type(8))) short;
using f32x4  = __attribute__((ext_vector_type(4))) float;

__device__ __forceinline__ float lrelu(float v) {
    return v > 0.f ? v : NEG_SLOPE * v;
}
__device__ __forceinline__ unsigned short bfb(float f) {
    __hip_bfloat16 h = __float2bfloat16(f);
    return *reinterpret_cast<unsigned short*>(&h);
}

// ---------- per-destination in-degree histogram (int atomics only) ----------
__global__ void k_count(const int* __restrict__ ei, int* __restrict__ cnt, int E) {
    int e = blockIdx.x * blockDim.x + threadIdx.x;
    if (e >= E) return;
    atomicAdd(&cnt[ei[E + e]], 1);
}

// ---------- hierarchical exclusive scan of cnt[N] -> off[N+1] ----------
__global__ void k_scan_part(const int* __restrict__ cnt, int* __restrict__ off,
                            int* __restrict__ bsum, int N) {
    __shared__ int sm[256];
    int i = blockIdx.x * 256 + threadIdx.x;
    int v = (i < N) ? cnt[i] : 0;
    sm[threadIdx.x] = v;
    __syncthreads();
    #pragma unroll
    for (int o = 1; o < 256; o <<= 1) {
        int t = (threadIdx.x >= (unsigned)o) ? sm[threadIdx.x - o] : 0;
        __syncthreads();
        sm[threadIdx.x] += t;
        __syncthreads();
    }
    if (i < N) off[i] = sm[threadIdx.x];
    if (threadIdx.x == 255) bsum[blockIdx.x] = sm[255];
}

__global__ void k_scan_top(int* __restrict__ bsum, int* __restrict__ off,
                           int NB, int N) {
    __shared__ int sm[256];
    int v = (threadIdx.x < (unsigned)NB) ? bsum[threadIdx.x] : 0;
    sm[threadIdx.x] = v;
    __syncthreads();
    #pragma unroll
    for (int o = 1; o < 256; o <<= 1) {
        int t = (threadIdx.x >= (unsigned)o) ? sm[threadIdx.x - o] : 0;
        __syncthreads();
        sm[threadIdx.x] += t;
        __syncthreads();
    }
    if (threadIdx.x < (unsigned)NB) bsum[threadIdx.x] = sm[threadIdx.x] - v;
    if (threadIdx.x == 255) off[N] = sm[255];
}

__global__ void k_scan_add(const int* __restrict__ cnt, int* __restrict__ off,
                           const int* __restrict__ bsum, int N) {
    int i = blockIdx.x * 256 + threadIdx.x;
    if (i < N) off[i] = off[i] - cnt[i] + bsum[blockIdx.x];
}

// ---------- CSR fill: adj2[slot] = {src, edge_id} (one 8B store) ----------
__global__ void k_fill(const int* __restrict__ ei, const int* __restrict__ off,
                       int* __restrict__ pos, int2* __restrict__ adj2, int E) {
    int e = blockIdx.x * blockDim.x + threadIdx.x;
    if (e >= E) return;
    int dst = ei[E + e];
    int slot = off[dst] + atomicAdd(&pos[dst], 1);
    adj2[slot] = make_int2(ei[e], e);
}

// ---------- weight prep: Wt[w][n][k] = bf16(W_w[k][n]) (transposed) ----------
// grid 16: b>>2 = weight (0=W_node, 1..3=lin_w), b&3 = 32-row k panel
__global__ __launch_bounds__(256) void k_wprep(
        const float* __restrict__ Wn, const float* __restrict__ lw,
        unsigned short* __restrict__ Wt) {
    __shared__ float Wf[32][132];
    int b = blockIdx.x, w = b >> 2, p = b & 3;
    const float* src = (w == 0) ? (Wn + (size_t)p * 32 * D)
                                : (lw + (size_t)(w - 1) * D * D + (size_t)p * 32 * D);
    int tid = threadIdx.x;
    #pragma unroll
    for (int j = 0; j < 4; j++) {
        int i = tid + j * 256;
        int r = i >> 5, q = i & 31;
        float4 v = reinterpret_cast<const float4*>(src)[i];
        *reinterpret_cast<float4*>(&Wf[r][q * 4]) = v;
    }
    __syncthreads();
    int n = tid & 127, ks = (tid >> 7) * 16;
    unsigned short t16[16];
    #pragma unroll
    for (int j = 0; j < 16; j++) t16[j] = bfb(Wf[ks + j][n]);
    unsigned short* dst = Wt + ((size_t)w * D + n) * D + p * 32 + ks;
    *reinterpret_cast<uint4*>(dst) = *reinterpret_cast<uint4*>(t16);
    *reinterpret_cast<uint4*>(dst + 8) = *reinterpret_cast<uint4*>(t16 + 8);
}

// ---------- MFMA GEMM: C[N,128] = bf16(A[N,128]) @ bf16(W[128,128]) ----------
// 64 rows/block, 256 threads = 4 waves; wave w: rows w*16..w*16+15, all 128
// cols (8 col-tiles x 4 k-steps of mfma_f32_16x16x32_bf16).
// MODE 1: A explicit (h), bf16 out + fused attention dots.
// MODE 2: A synthesized from scatter-mean, f32 out + bias.
template <int MODE>
__global__ __launch_bounds__(256) void k_gemm(
        const float* __restrict__ A, const unsigned short* __restrict__ Wt,
        const float* __restrict__ bias, float* __restrict__ C,
        __hip_bfloat16* __restrict__ xhb, float* __restrict__ a_s,
        float* __restrict__ a_d, const float* __restrict__ att_s,
        const float* __restrict__ att_d,
        const float* __restrict__ x, const int2* __restrict__ adj2,
        const int* __restrict__ off,
        const float* __restrict__ W_edge, const float* __restrict__ b_edge,
        int N) {
    __shared__ __align__(16) unsigned short AsB[64 * LDA];   // 17.4 KB
    __shared__ __align__(16) unsigned short WtB[128 * LDA];  // 34.8 KB (reused f32 [64][LDE] in epilogue)
    int tid = threadIdx.x;
    int n0 = blockIdx.x * 64;

    // stage Wt (pre-transposed bf16 [128][128]) -> LDS [128][LDA]
    #pragma unroll
    for (int j = 0; j < 8; j++) {
        int ch = tid + j * 256;
        int r = ch >> 4, c = ch & 15;
        uint4 v = *reinterpret_cast<const uint4*>(Wt + (size_t)r * D + c * 8);
        *reinterpret_cast<uint4*>(&WtB[r * LDA + c * 8]) = v;
    }

    if (MODE == 2) {
        __shared__ float rowf[64][4];
        {
            int r = tid >> 2, t4 = tid & 3;
            int n = n0 + r;
            float s0 = 0.f, s1 = 0.f, s2 = 0.f;
            int degv = 0;
            if (n < N) {
                int beg = off[n], end = off[n + 1];
                degv = end - beg;
                for (int p = beg + t4; p < end; p += 4) {
                    const float* xr = x + (size_t)adj2[p].y * 3;
                    s0 += xr[0]; s1 += xr[1]; s2 += xr[2];
                }
            }
            s0 += __shfl_xor(s0, 1); s0 += __shfl_xor(s0, 2);
            s1 += __shfl_xor(s1, 1); s1 += __shfl_xor(s1, 2);
            s2 += __shfl_xor(s2, 1); s2 += __shfl_xor(s2, 2);
            if (t4 == 0)
                *reinterpret_cast<float4*>(rowf[r]) =
                    make_float4(s0, s1, s2, (float)degv);
        }
        __syncthreads();
        #pragma unroll
        for (int j = 0; j < 4; j++) {
            int ch = tid + j * 256;
            int r = ch >> 4, c = ch & 15;
            float4 rv = *reinterpret_cast<float4*>(rowf[r]);
            float cn = rv.w, rc = 1.f / fmaxf(cn, 1.f);
            int d0 = c * 8;
            unsigned short t8[8];
            #pragma unroll
            for (int q = 0; q < 2; q++) {
                float4 we0 = *reinterpret_cast<const float4*>(W_edge + d0 + q * 4);
                float4 we1 = *reinterpret_cast<const float4*>(W_edge + D + d0 + q * 4);
                float4 we2 = *reinterpret_cast<const float4*>(W_edge + 2 * D + d0 + q * 4);
                float4 be  = *reinterpret_cast<const float4*>(b_edge + d0 + q * 4);
                t8[q * 4 + 0] = bfb((rv.x * we0.x + rv.y * we1.x + rv.z * we2.x + cn * be.x) * rc);
                t8[q * 4 + 1] = bfb((rv.x * we0.y + rv.y * we1.y + rv.z * we2.y + cn * be.y) * rc);
                t8[q * 4 + 2] = bfb((rv.x * we0.z + rv.y * we1.z + rv.z * we2.z + cn * be.z) * rc);
                t8[q * 4 + 3] = bfb((rv.x * we0.w + rv.y * we1.w + rv.z * we2.w + cn * be.w) * rc);
            }
            *reinterpret_cast<uint4*>(&AsB[r * LDA + c * 8]) =
                *reinterpret_cast<uint4*>(t8);
        }
    } else {
        #pragma unroll
        for (int j = 0; j < 4; j++) {
            int ch = tid + j * 256;
            int r = ch >> 4, c = ch & 15;
            int n = n0 + r;
            float4 v0 = make_float4(0.f, 0.f, 0.f, 0.f), v1 = v0;
            if (n < N) {
                v0 = reinterpret_cast<const float4*>(A)[(size_t)n * 32 + c * 2];
                v1 = reinterpret_cast<const float4*>(A)[(size_t)n * 32 + c * 2 + 1];
            }
            unsigned short t8[8] = {bfb(v0.x), bfb(v0.y), bfb(v0.z), bfb(v0.w),
                                    bfb(v1.x), bfb(v1.y), bfb(v1.z), bfb(v1.w)};
            *reinterpret_cast<uint4*>(&AsB[r * LDA + c * 8]) =
                *reinterpret_cast<uint4*>(t8);
        }
    }
    __syncthreads();

    // MFMA: lane layout: lrow = lane&15 (row/col in tile), lk = lane>>4 (k-grp)
    int lane = tid & 63, wv = tid >> 6;
    int lrow = lane & 15, lk = lane >> 4;
    f32x4 acc[8];
    #pragma unroll
    for (int ct = 0; ct < 8; ct++) acc[ct] = (f32x4){0.f, 0.f, 0.f, 0.f};
    int arow = wv * 16 + lrow;
    #pragma unroll
    for (int ks = 0; ks < 4; ks++) {
        bf16x8 af = *reinterpret_cast<const bf16x8*>(
            &AsB[arow * LDA + ks * 32 + lk * 8]);
        #pragma unroll
        for (int ct = 0; ct < 8; ct++) {
            bf16x8 bfr = *reinterpret_cast<const bf16x8*>(
                &WtB[(ct * 16 + lrow) * LDA + ks * 32 + lk * 8]);
            acc[ct] = __builtin_amdgcn_mfma_f32_16x16x32_bf16(af, bfr, acc[ct], 0, 0, 0);
        }
    }
    __syncthreads();   // all reads of AsB/WtB done; reuse WtB as f32 staging

    // transpose acc through LDS: D row = (lane>>4)*4+j, col = lane&15
    float* Ef = reinterpret_cast<float*>(WtB);
    #pragma unroll
    for (int ct = 0; ct < 8; ct++)
        #pragma unroll
        for (int j = 0; j < 4; j++)
            Ef[(wv * 16 + lk * 4 + j) * LDE + ct * 16 + lrow] = acc[ct][j];
    __syncthreads();

    int tx = tid & 15, ty = tid >> 4;
    int c0 = tx * 8, r0 = ty * 4;
    float o[4][8];
    #pragma unroll
    for (int r = 0; r < 4; r++) {
        float4 v0 = *reinterpret_cast<const float4*>(&Ef[(r0 + r) * LDE + c0]);
        float4 v1 = *reinterpret_cast<const float4*>(&Ef[(r0 + r) * LDE + c0 + 4]);
        o[r][0] = v0.x; o[r][1] = v0.y; o[r][2] = v0.z; o[r][3] = v0.w;
        o[r][4] = v1.x; o[r][5] = v1.y; o[r][6] = v1.z; o[r][7] = v1.w;
    }

    if (MODE == 2) {
        float b[8];
        #pragma unroll
        for (int c = 0; c < 8; c++) b[c] = bias[c0 + c];
        #pragma unroll
        for (int r = 0; r < 4; r++) {
            int n = n0 + r0 + r;
            if (n >= N) continue;
            float4 o0 = make_float4(o[r][0] + b[0], o[r][1] + b[1],
                                    o[r][2] + b[2], o[r][3] + b[3]);
            float4 o1 = make_float4(o[r][4] + b[4], o[r][5] + b[5],
                                    o[r][6] + b[6], o[r][7] + b[7]);
            reinterpret_cast<float4*>(C)[(size_t)n * 32 + tx * 2] = o0;
            reinterpret_cast<float4*>(C)[(size_t)n * 32 + tx * 2 + 1] = o1;
        }
    } else {
        float ats[8], atd[8];
        #pragma unroll
        for (int c = 0; c < 8; c++) { ats[c] = att_s[c0 + c]; atd[c] = att_d[c0 + c]; }
        #pragma unroll
        for (int r = 0; r < 4; r++) {
            int n = n0 + r0 + r;
            union { uint4 v; unsigned short s[8]; } pk;
            #pragma unroll
            for (int c = 0; c < 8; c++) pk.s[c] = bfb(o[r][c]);
            float ps = 0.f, pd = 0.f;
            #pragma unroll
            for (int c = 0; c < 8; c++) { ps += o[r][c] * ats[c]; pd += o[r][c] * atd[c]; }
            ps += __shfl_xor(ps, 1); ps += __shfl_xor(ps, 2);
            pd += __shfl_xor(pd, 1); pd += __shfl_xor(pd, 2);
            if (n < N) {
                *reinterpret_cast<uint4*>(xhb + (size_t)n * D + c0) = pk.v;
                if ((tx & 3) == 0) {
                    a_s[n * H + (tx >> 2)] = ps;
                    a_d[n * H + (tx >> 2)] = pd;
                }
            }
        }
    }
}

// ---------- fused GAT aggregate + bias + LN (+ReLU) + residual ----------
// One wave per node, 4 nodes per 256-thread block (R6 config). SINGLE PASS:
// no segment-max (lrelu-bounded logits -> exp safe in f32), no LDS.
__global__ __launch_bounds__(256) void k_gat5(
        const __hip_bfloat16* __restrict__ xhb, const int* __restrict__ off,
        const int2* __restrict__ adj2, const float* __restrict__ a_s,
        const float* __restrict__ a_d, const float* __restrict__ bias,
        const float* __restrict__ g, const float* __restrict__ bln,
        float* __restrict__ h, int N, int do_relu) {
    int wid = threadIdx.x >> 6;
    int lane = threadIdx.x & 63;
    int n = blockIdx.x * 4 + wid;
    if (n >= N) return;

    int cl = lane & 15;             // channel group: c0 = 8*cl
    int sub = lane >> 4;            // edge sub-slot (4 edges in flight)
    int hb = cl >> 2;               // head of this lane's channels
    int c0 = cl * 8;

    int beg = off[n], end = off[n + 1];
    int deg = end - beg;
    int items = deg + 1;            // + self loop
    int itp = (items + 3) & ~3;

    float adA = a_d[n * H + hb];
    float den = 0.f;
    float acc[8];
    #pragma unroll
    for (int c = 0; c < 8; c++) acc[c] = 0.f;

    #pragma unroll 4
    for (int pp = sub; pp < itp; pp += 4) {
        int s = (pp < deg) ? adj2[beg + pp].x : n;
        float av = a_s[(size_t)s * H + hb];
        uint4 u = *reinterpret_cast<const uint4*>(xhb + (size_t)s * D + c0);
        float e = lrelu(av + adA);
        float wv = (pp < items) ? __expf(e) : 0.f;
        den += wv;
        float f;
        f = __uint_as_float(u.x << 16);         acc[0] += wv * f;
        f = __uint_as_float(u.x & 0xffff0000u); acc[1] += wv * f;
        f = __uint_as_float(u.y << 16);         acc[2] += wv * f;
        f = __uint_as_float(u.y & 0xffff0000u); acc[3] += wv * f;
        f = __uint_as_float(u.z << 16);         acc[4] += wv * f;
        f = __uint_as_float(u.z & 0xffff0000u); acc[5] += wv * f;
        f = __uint_as_float(u.w << 16);         acc[6] += wv * f;
        f = __uint_as_float(u.w & 0xffff0000u); acc[7] += wv * f;
    }

    #pragma unroll
    for (int c = 0; c < 8; c++) {
        acc[c] += __shfl_xor(acc[c], 16);
        acc[c] += __shfl_xor(acc[c], 32);
    }
    den += __shfl_xor(den, 16);
    den += __shfl_xor(den, 32);
    float rden = 1.0f / den;

    float4 b0 = *reinterpret_cast<const float4*>(bias + c0);
    float4 b1 = *reinterpret_cast<const float4*>(bias + c0 + 4);
    float o[8];
    o[0] = acc[0] * rden + b0.x; o[1] = acc[1] * rden + b0.y;
    o[2] = acc[2] * rden + b0.z; o[3] = acc[3] * rden + b0.w;
    o[4] = acc[4] * rden + b1.x; o[5] = acc[5] * rden + b1.y;
    o[6] = acc[6] * rden + b1.z; o[7] = acc[7] * rden + b1.w;

    float s1 = 0.f;
    #pragma unroll
    for (int c = 0; c < 8; c++) s1 += o[c];
    #pragma unroll
    for (int os = 1; os < 64; os <<= 1) s1 += __shfl_xor(s1, os);
    float mu = s1 * (1.0f / 512.0f);
    float s2 = 0.f;
    #pragma unroll
    for (int c = 0; c < 8; c++) { float dv = o[c] - mu; s2 += dv * dv; }
    #pragma unroll
    for (int os = 1; os < 64; os <<= 1) s2 += __shfl_xor(s2, os);
    float inv = rsqrtf(s2 * (1.0f / 512.0f) + LN_EPS);

    if (sub == 0) {
        float4 g0 = *reinterpret_cast<const float4*>(g + c0);
        float4 g1 = *reinterpret_cast<const float4*>(g + c0 + 4);
        float4 l0 = *reinterpret_cast<const float4*>(bln + c0);
        float4 l1 = *reinterpret_cast<const float4*>(bln + c0 + 4);
        float y[8];
        y[0] = (o[0] - mu) * inv * g0.x + l0.x;
        y[1] = (o[1] - mu) * inv * g0.y + l0.y;
        y[2] = (o[2] - mu) * inv * g0.z + l0.z;
        y[3] = (o[3] - mu) * inv * g0.w + l0.w;
        y[4] = (o[4] - mu) * inv * g1.x + l1.x;
        y[5] = (o[5] - mu) * inv * g1.y + l1.y;
        y[6] = (o[6] - mu) * inv * g1.z + l1.z;
        y[7] = (o[7] - mu) * inv * g1.w + l1.w;
        if (do_relu) {
            #pragma unroll
            for (int c = 0; c < 8; c++) y[c] = fmaxf(y[c], 0.f);
        }
        float4 h0 = *reinterpret_cast<float4*>(h + (size_t)n * D + c0);
        float4 h1 = *reinterpret_cast<float4*>(h + (size_t)n * D + c0 + 4);
        h0.x += y[0]; h0.y += y[1]; h0.z += y[2]; h0.w += y[3];
        h1.x += y[4]; h1.y += y[5]; h1.z += y[6]; h1.w += y[7];
        *reinterpret_cast<float4*>(h + (size_t)n * D + c0) = h0;
        *reinterpret_cast<float4*>(h + (size_t)n * D + c0 + 4) = h1;
    }
}

extern "C" void kernel_launch(void* const* d_in, const int* in_sizes, int n_in,
                              void* d_out, int out_size, void* d_ws, size_t ws_size,
                              hipStream_t stream) {
    const float* x       = (const float*)d_in[0];
    const int*   ei      = (const int*)  d_in[1];
    const float* W_edge  = (const float*)d_in[2];
    const float* b_edge  = (const float*)d_in[3];
    const float* W_node  = (const float*)d_in[4];
    const float* b_node  = (const float*)d_in[5];
    const float* lin_w   = (const float*)d_in[6];
    const float* att_src = (const float*)d_in[7];
    const float* att_dst = (const float*)d_in[8];
    const float* gat_b   = (const float*)d_in[9];
    const float* ln_g    = (const float*)d_in[10];
    const float* ln_b    = (const float*)d_in[11];

    int N = out_size / D;
    int E = in_sizes[1] / 2;
    int NB = (N + 255) / 256;

    char* w = (char*)d_ws;
    auto carve = [&](size_t bytes) {
        void* p = (void*)w;
        w += (bytes + 255) & ~(size_t)255;
        return p;
    };
    int*   cnt  = (int*)  carve((size_t)N * 4);
    int*   pos  = (int*)  carve((size_t)N * 4);
    int*   off  = (int*)  carve((size_t)(N + 1) * 4);
    int2*  adj2 = (int2*) carve((size_t)E * 8);
    int*   bsum = (int*)  carve((size_t)NB * 4);
    float* tmp  = (float*)carve((size_t)N * D * 4);
    float* a_s  = (float*)carve((size_t)N * H * 4);
    float* a_d  = (float*)carve((size_t)N * H * 4);
    unsigned short* Wt = (unsigned short*)carve((size_t)4 * D * D * 2);
    __hip_bfloat16* xhb = (__hip_bfloat16*)tmp;

    float* h = (float*)d_out;

    hipMemsetAsync(cnt, 0, (size_t)N * 4, stream);
    hipMemsetAsync(pos, 0, (size_t)N * 4, stream);

    int tb = 256;
    k_wprep<<<16, 256, 0, stream>>>(W_node, lin_w, Wt);
    k_count<<<(E + tb - 1) / tb, tb, 0, stream>>>(ei, cnt, E);
    k_scan_part<<<NB, 256, 0, stream>>>(cnt, off, bsum, N);
    k_scan_top<<<1, 256, 0, stream>>>(bsum, off, NB, N);
    k_scan_add<<<NB, 256, 0, stream>>>(cnt, off, bsum, N);
    k_fill<<<(E + tb - 1) / tb, tb, 0, stream>>>(ei, off, pos, adj2, E);
    k_gemm<2><<<(N + 63) / 64, 256, 0, stream>>>(
        nullptr, Wt, b_node, h, nullptr, nullptr, nullptr, nullptr, nullptr,
        x, adj2, off, W_edge, b_edge, N);

    for (int i = 0; i < 3; i++) {
        k_gemm<1><<<(N + 63) / 64, 256, 0, stream>>>(
            h, Wt + (size_t)(i + 1) * D * D, nullptr, nullptr,
            xhb, a_s, a_d, att_src + i * D, att_dst + i * D,
            nullptr, nullptr, nullptr, nullptr, nullptr, N);
        k_gat5<<<(N + 3) / 4, 256, 0, stream>>>(
            xhb, off, adj2, a_s, a_d,
            gat_b + i * D, ln_g + i * D, ln_b + i * D,
            h, N, (i < 2) ? 1 : 0);
    }
}